// Round 1
// baseline (607.537 us; speedup 1.0000x reference)
//
#include <hip/hip_runtime.h>

// Problem constants (B=64, D=256, H=W=32, K=1024)
#define DDIM 256
#define KCODES 1024
#define HW 1024
#define NTOK 65536
#define OUTOFF 16777216   // NTOK*DDIM; second tuple element offset

// ---------------------------------------------------------------------------
// Kernel 1: cbn[k] = 0.5 * ||codebook[k]||^2   (1024 rows of 256)
// ---------------------------------------------------------------------------
__global__ __launch_bounds__(64) void cbnorm_kernel(const float* __restrict__ cb,
                                                    float* __restrict__ cbn) {
    const int k = blockIdx.x;
    const int l = threadIdx.x;
    const float4 v = *reinterpret_cast<const float4*>(cb + k * DDIM + 4 * l);
    float s = v.x * v.x + v.y * v.y + v.z * v.z + v.w * v.w;
    #pragma unroll
    for (int m = 32; m >= 1; m >>= 1) s += __shfl_xor(s, m, 64);
    if (l == 0) cbn[k] = 0.5f * s;
}

// ---------------------------------------------------------------------------
// Kernel 2: fused distance-GEMM + argmin + gather-write.
// Block tile: 128 tokens x (all K, in 8 tiles of 128 codes), D in tiles of 32.
// Thread (i = t>>4, j = t&15) owns tokens {4i..4i+3, 64+4i..} and codes
// {4j..4j+3, 64+4j..} -> 8x8 register accumulator, all LDS b128 reads are
// <=2-way bank-aliased (free).
// ---------------------------------------------------------------------------
__global__ __launch_bounds__(256, 2) void vq_kernel(const float* __restrict__ x,
                                                    const float* __restrict__ cb,
                                                    const float* __restrict__ cbn,
                                                    float* __restrict__ out) {
    __shared__ __align__(16) float xs[32][128];   // [d_rel][token_rel]
    __shared__ __align__(16) float cbs[32][128];  // [d_rel][code_rel]
    __shared__ float cbn_s[KCODES];
    __shared__ int idx_lds[128];

    const int t = threadIdx.x;
    const int i = t >> 4;            // token-row group 0..15
    const int j = t & 15;            // code-col group 0..15
    const int bidx = blockIdx.x;     // 0..511
    const int b = bidx >> 3;         // batch 0..63
    const int hw0 = (bidx & 7) << 7; // 0..896 step 128
    const int n0 = b * HW + hw0;     // first global token of this block
    const float* xb = x + (size_t)b * (DDIM * HW) + hw0;

    // preload 0.5*||c||^2 into LDS (visible after the first __syncthreads)
    {
        float4 v = *reinterpret_cast<const float4*>(cbn + 4 * t);
        *reinterpret_cast<float4*>(&cbn_s[4 * t]) = v;
    }

    // staging assignments
    const int xs_row = t >> 3;         // 0..31
    const int xs_col = (t & 7) << 4;   // 0..112 step 16
    const int cb_k = t & 127;          // code within tile
    const int cb_dh = (t >> 7) << 4;   // 0 or 16 (d half)

    float bestv[8];
    int besti[8];
    #pragma unroll
    for (int a = 0; a < 8; ++a) { bestv[a] = 3.4e38f; besti[a] = 0; }

    for (int kt = 0; kt < 8; ++kt) {
        const int k0 = kt << 7;
        float acc[8][8];
        #pragma unroll
        for (int a = 0; a < 8; ++a)
            #pragma unroll
            for (int c = 0; c < 8; ++c) acc[a][c] = 0.0f;

        for (int dt = 0; dt < 8; ++dt) {
            const int d0 = dt << 5;
            // ---- stage x tile [32][128]: contiguous rows, no transpose ----
            {
                const float* xg = xb + (size_t)(d0 + xs_row) * HW + xs_col;
                #pragma unroll
                for (int q = 0; q < 4; ++q) {
                    float4 v = *reinterpret_cast<const float4*>(xg + 4 * q);
                    *reinterpret_cast<float4*>(&xs[xs_row][xs_col + 4 * q]) = v;
                }
            }
            // ---- stage cb tile [32][128] with register transpose ----
            {
                const float* cg = cb + (size_t)(k0 + cb_k) * DDIM + d0 + cb_dh;
                #pragma unroll
                for (int q = 0; q < 4; ++q) {
                    float4 v = *reinterpret_cast<const float4*>(cg + 4 * q);
                    cbs[cb_dh + 4 * q + 0][cb_k] = v.x;
                    cbs[cb_dh + 4 * q + 1][cb_k] = v.y;
                    cbs[cb_dh + 4 * q + 2][cb_k] = v.z;
                    cbs[cb_dh + 4 * q + 3][cb_k] = v.w;
                }
            }
            __syncthreads();
            // ---- inner product over 32 d's: 4 b128 reads + 64 FMA per d ----
            #pragma unroll 4
            for (int d = 0; d < 32; ++d) {
                float4 xa = *reinterpret_cast<const float4*>(&xs[d][4 * i]);
                float4 xc = *reinterpret_cast<const float4*>(&xs[d][64 + 4 * i]);
                float4 ca = *reinterpret_cast<const float4*>(&cbs[d][4 * j]);
                float4 cc = *reinterpret_cast<const float4*>(&cbs[d][64 + 4 * j]);
                float xr[8] = {xa.x, xa.y, xa.z, xa.w, xc.x, xc.y, xc.z, xc.w};
                float cr[8] = {ca.x, ca.y, ca.z, ca.w, cc.x, cc.y, cc.z, cc.w};
                #pragma unroll
                for (int a = 0; a < 8; ++a)
                    #pragma unroll
                    for (int c = 0; c < 8; ++c)
                        acc[a][c] = fmaf(xr[a], cr[c], acc[a][c]);
            }
            __syncthreads();
        }
        // ---- min-update epilogue (registers only) ----
        #pragma unroll
        for (int c = 0; c < 8; ++c) {
            const int kk = k0 + ((c < 4) ? (4 * j + c) : (64 + 4 * j + (c - 4)));
            const float cn = cbn_s[kk];
            #pragma unroll
            for (int a = 0; a < 8; ++a) {
                const float dv = cn - acc[a][c];
                if (dv < bestv[a] || (dv == bestv[a] && kk < besti[a])) {
                    bestv[a] = dv;
                    besti[a] = kk;
                }
            }
        }
    }

    // ---- cross-lane argmin over the 16-lane code group (first-index ties) ----
    #pragma unroll
    for (int a = 0; a < 8; ++a) {
        #pragma unroll
        for (int m = 1; m < 16; m <<= 1) {
            const float ov = __shfl_xor(bestv[a], m, 64);
            const int oi = __shfl_xor(besti[a], m, 64);
            if (ov < bestv[a] || (ov == bestv[a] && oi < besti[a])) {
                bestv[a] = ov;
                besti[a] = oi;
            }
        }
    }
    if (j == 0) {
        #pragma unroll
        for (int a = 0; a < 8; ++a) {
            const int row = (a < 4) ? (4 * i + a) : (64 + 4 * i + (a - 4));
            idx_lds[row] = besti[a];
        }
    }
    __syncthreads();

    // ---- gather + write both outputs; one 1KB row per wave-instruction ----
    const int w = t >> 6;  // wave 0..3
    const int l = t & 63;
    for (int rr = 0; rr < 32; ++rr) {
        const int row = (w << 5) + rr;
        const int kidx = idx_lds[row];
        const float4 v =
            *reinterpret_cast<const float4*>(cb + (size_t)kidx * DDIM + 4 * l);
        const size_t n = (size_t)(n0 + row);
        *reinterpret_cast<float4*>(out + n * DDIM + 4 * l) = v;
        *reinterpret_cast<float4*>(out + OUTOFF + n * DDIM + 4 * l) = v;
    }
}

extern "C" void kernel_launch(void* const* d_in, const int* in_sizes, int n_in,
                              void* d_out, int out_size, void* d_ws, size_t ws_size,
                              hipStream_t stream) {
    const float* x = (const float*)d_in[0];
    const float* cb = (const float*)d_in[1];
    float* out = (float*)d_out;
    float* cbn = (float*)d_ws;  // 1024 floats of scratch

    cbnorm_kernel<<<KCODES, 64, 0, stream>>>(cb, cbn);
    vq_kernel<<<512, 256, 0, stream>>>(x, cb, cbn, out);
}

// Round 3
// 389.059 us; speedup vs baseline: 1.5616x; 1.5616x over previous
//
#include <hip/hip_runtime.h>
#include <cstdint>

// Problem: B=64, D=256, H=W=32, K=1024  ->  N = 65536 tokens.
// argmin_k ||x-c_k||^2 == argmin_k (0.5*||c_k||^2 - x.c_k)
//
// Scratch layout inside d_out (float offsets; all regions disjoint, see notes):
//   idx[token]  : out[token*256]          (int bits; inside gather-block's own row)
//   counter     : out[32]                 (int)
//   list[i]     : out[i*256 + 64]         (int token id)
//   cb_hi row k : bytes k*1024+512 .. +512       (256 bf16)
//   cb_lo row k : bytes (1024+k)*1024+512 ..     (256 bf16)
//   cbn[k]      : out[(2048+k)*256 + 128]        (0.5*||c_k||^2, fp32)
//   x_hi tok n  : bytes XHI_B + n*512            (256 bf16, token-major)
//   x_lo tok n  : bytes XLO_B + n*512
#define OUTOFF 16777216ULL
#define XHI_B 67108864ULL
#define XLO_B 100663296ULL
#define EPS 0.025f

typedef short bf16x8 __attribute__((ext_vector_type(8)));
typedef float f32x4 __attribute__((ext_vector_type(4)));

__device__ __forceinline__ unsigned short f2bf(float f) {
  unsigned int u = __float_as_uint(f);
  u += 0x7FFFu + ((u >> 16) & 1u);
  return (unsigned short)(u >> 16);
}
__device__ __forceinline__ float bf2f(unsigned short h) {
  return __uint_as_float(((unsigned int)h) << 16);
}
__device__ __forceinline__ void gload16(const void* g, void* l) {
  __builtin_amdgcn_global_load_lds(
      (const unsigned int __attribute__((address_space(1)))*)(unsigned long long)(uintptr_t)g,
      (unsigned int __attribute__((address_space(3)))*)(unsigned int)(uintptr_t)l, 16, 0, 0);
}

// ---------------------------------------------------------------------------
// k1: cbn + codebook hi/lo split + zero flag counter
// ---------------------------------------------------------------------------
__global__ __launch_bounds__(64) void prep(const float* __restrict__ cb,
                                           float* __restrict__ outp) {
  const int k = blockIdx.x, l = threadIdx.x;
  if (k == 0 && l == 0) ((int*)outp)[32] = 0;
  const float4 v = *reinterpret_cast<const float4*>(cb + k * 256 + l * 4);
  float s = v.x * v.x + v.y * v.y + v.z * v.z + v.w * v.w;
  #pragma unroll
  for (int m = 32; m >= 1; m >>= 1) s += __shfl_xor(s, m, 64);
  if (l == 0) outp[(size_t)(2048 + k) * 256 + 128] = 0.5f * s;
  unsigned short h0 = f2bf(v.x), h1 = f2bf(v.y), h2 = f2bf(v.z), h3 = f2bf(v.w);
  ushort4 hh = {h0, h1, h2, h3};
  ushort4 ll = {f2bf(v.x - bf2f(h0)), f2bf(v.y - bf2f(h1)),
                f2bf(v.z - bf2f(h2)), f2bf(v.w - bf2f(h3))};
  char* ob = (char*)outp;
  *reinterpret_cast<ushort4*>(ob + (size_t)k * 1024 + 512 + l * 8) = hh;
  *reinterpret_cast<ushort4*>(ob + (size_t)(1024 + k) * 1024 + 512 + l * 8) = ll;
}

// ---------------------------------------------------------------------------
// k2: x [d][tok] fp32 -> token-major bf16 hi/lo via LDS transpose
// ---------------------------------------------------------------------------
__global__ __launch_bounds__(256) void xsplit(const float* __restrict__ x,
                                              float* __restrict__ outp) {
  __shared__ __align__(16) float sX[16384];  // [256 d][64 tok], chunk-XOR swizzled
  const int t = threadIdx.x;
  const int n0 = blockIdx.x << 6;
  const int b = n0 >> 10, hw0 = n0 & 1023;
  const float* xb = x + (size_t)b * 262144 + hw0;
  float4* sX4 = reinterpret_cast<float4*>(sX);
  #pragma unroll
  for (int r = 0; r < 16; ++r) {
    const int d = r * 16 + (t >> 4);
    const int T = t & 15;
    const float4 v = *reinterpret_cast<const float4*>(xb + (size_t)d * 1024 + T * 4);
    sX4[d * 16 + (T ^ ((d >> 3) & 15))] = v;
  }
  __syncthreads();
  char* xh = (char*)outp + XHI_B;
  char* xl = (char*)outp + XLO_B;
  #pragma unroll 1
  for (int p = 0; p < 8; ++p) {
    const int tl = p * 8 + (t >> 5);  // token local 0..63
    const int c = t & 31;             // d-chunk: d = c*8..c*8+7
    const int Tr = tl >> 2, ri = tl & 3;
    uint4 H, L;
    unsigned int hw_[4], lw_[4];
    #pragma unroll
    for (int qq = 0; qq < 4; ++qq) {
      const int d0 = c * 8 + qq * 2;
      const float v0 = sX[d0 * 64 + ((Tr ^ (c & 15)) << 2) + ri];
      const float v1 = sX[(d0 + 1) * 64 + ((Tr ^ (c & 15)) << 2) + ri];
      const unsigned short a0 = f2bf(v0), a1 = f2bf(v1);
      hw_[qq] = (unsigned int)a0 | ((unsigned int)a1 << 16);
      lw_[qq] = (unsigned int)f2bf(v0 - bf2f(a0)) |
                ((unsigned int)f2bf(v1 - bf2f(a1)) << 16);
    }
    H.x = hw_[0]; H.y = hw_[1]; H.z = hw_[2]; H.w = hw_[3];
    L.x = lw_[0]; L.y = lw_[1]; L.z = lw_[2]; L.w = lw_[3];
    const size_t off = (size_t)(n0 + tl) * 512 + c * 16;
    *reinterpret_cast<uint4*>(xh + off) = H;
    *reinterpret_cast<uint4*>(xl + off) = L;
  }
}

// ---------------------------------------------------------------------------
// k3: fused bf16 MFMA distance-GEMM (3-pass hi/lo) + top-2 argmin
// 512 blocks x 512 thr (8 waves). Tile 128 tok x 128 codes, BK=64, D=256.
// ---------------------------------------------------------------------------
__global__ __launch_bounds__(512, 4) void vq_mfma(float* __restrict__ outp) {
  __shared__ __align__(16) unsigned short sXhi[8192], sXlo[8192], sChi[8192], sClo[8192];
  char* outb = (char*)outp;
  int* outi = (int*)outp;
  const int t = threadIdx.x;
  const int w = t >> 6, l = t & 63;
  const int wm = w & 3, wn = w >> 2;
  const int token0 = blockIdx.x << 7;
  const int lr = l >> 3, lc = l & 7;
  const int chp = lc ^ lr;          // staging source chunk (pre-swizzled)
  const int col = l & 15, g = l >> 4, e7 = l & 7;
  const int srow = w << 4;          // wave's 16 staging rows

  f32x4 acc[2][4];
  float b1[8], b2[8];
  int bi[8];
  #pragma unroll
  for (int r = 0; r < 8; ++r) { b1[r] = 3.4e38f; b2[r] = 3.4e38f; bi[r] = 0; }

  #pragma unroll 1
  for (int kt = 0; kt < 8; ++kt) {
    #pragma unroll
    for (int mf = 0; mf < 2; ++mf)
      #pragma unroll
      for (int nf = 0; nf < 4; ++nf) acc[mf][nf] = (f32x4){0.f, 0.f, 0.f, 0.f};

    #pragma unroll 1
    for (int dt = 0; dt < 4; ++dt) {
      __syncthreads();
      #pragma unroll
      for (int q = 0; q < 2; ++q) {
        const int row = srow + (q << 3);
        const int grow = row + lr;
        const size_t xoff = (size_t)(token0 + grow) * 512 + (size_t)(dt * 128 + chp * 16);
        gload16(outb + XHI_B + xoff, &sXhi[row * 64]);
        gload16(outb + XLO_B + xoff, &sXlo[row * 64]);
        const size_t coff =
            (size_t)(kt * 128 + grow) * 1024 + 512 + (size_t)(dt * 128 + chp * 16);
        gload16(outb + coff, &sChi[row * 64]);
        gload16(outb + coff + 1048576, &sClo[row * 64]);
      }
      __syncthreads();
      #pragma unroll
      for (int ks = 0; ks < 2; ++ks) {
        bf16x8 ah[2], al[2], bh[4], bl[4];
        const int ch = ((ks << 2) + g) ^ e7;
        #pragma unroll
        for (int mf = 0; mf < 2; ++mf) {
          const int ae = (wm * 32 + mf * 16 + col) * 64 + ch * 8;
          ah[mf] = *reinterpret_cast<const bf16x8*>(&sXhi[ae]);
          al[mf] = *reinterpret_cast<const bf16x8*>(&sXlo[ae]);
        }
        #pragma unroll
        for (int nf = 0; nf < 4; ++nf) {
          const int be = (wn * 64 + nf * 16 + col) * 64 + ch * 8;
          bh[nf] = *reinterpret_cast<const bf16x8*>(&sChi[be]);
          bl[nf] = *reinterpret_cast<const bf16x8*>(&sClo[be]);
        }
        #pragma unroll
        for (int mf = 0; mf < 2; ++mf)
          #pragma unroll
          for (int nf = 0; nf < 4; ++nf) {
            acc[mf][nf] = __builtin_amdgcn_mfma_f32_16x16x32_bf16(ah[mf], bh[nf], acc[mf][nf], 0, 0, 0);
            acc[mf][nf] = __builtin_amdgcn_mfma_f32_16x16x32_bf16(ah[mf], bl[nf], acc[mf][nf], 0, 0, 0);
            acc[mf][nf] = __builtin_amdgcn_mfma_f32_16x16x32_bf16(al[mf], bh[nf], acc[mf][nf], 0, 0, 0);
          }
      }
    }
    // epilogue: dist = cbn - x.c ; top-2 update
    #pragma unroll
    for (int nf = 0; nf < 4; ++nf) {
      const int code = kt * 128 + wn * 64 + nf * 16 + col;
      const float cn = outp[(size_t)(2048 + code) * 256 + 128];
      #pragma unroll
      for (int mf = 0; mf < 2; ++mf)
        #pragma unroll
        for (int r = 0; r < 4; ++r) {
          const float v = cn - acc[mf][nf][r];
          const int ridx = mf * 4 + r;
          if (v < b1[ridx]) {
            b2[ridx] = b1[ridx]; b1[ridx] = v; bi[ridx] = code;
          } else if (v < b2[ridx]) {
            b2[ridx] = v;
          } else if (v == b1[ridx]) {
            b2[ridx] = v;  // duplicate min value -> zero margin -> recheck
          }
        }
    }
  }

  // cross-lane top-2 reduce over the 16 code-lanes
  #pragma unroll
  for (int r = 0; r < 8; ++r) {
    #pragma unroll
    for (int m = 1; m < 16; m <<= 1) {
      const float o1 = __shfl_xor(b1[r], m, 64);
      const float o2 = __shfl_xor(b2[r], m, 64);
      const int oi = __shfl_xor(bi[r], m, 64);
      if (o1 < b1[r] || (o1 == b1[r] && oi < bi[r])) {
        b2[r] = fminf(b1[r], o2); b1[r] = o1; bi[r] = oi;
      } else {
        b2[r] = fminf(b2[r], o1);
      }
    }
  }
  // cross-wave combine (alias small buffers onto dead sXhi region)
  float* sB1 = reinterpret_cast<float*>(sXhi);  // [2][128]
  float* sB2 = sB1 + 256;
  int* sBi = reinterpret_cast<int*>(sB2 + 256);
  __syncthreads();
  if (col == 0) {
    #pragma unroll
    for (int r = 0; r < 8; ++r) {
      const int row = wm * 32 + (r >> 2) * 16 + g * 4 + (r & 3);
      sB1[wn * 128 + row] = b1[r];
      sB2[wn * 128 + row] = b2[r];
      sBi[wn * 128 + row] = bi[r];
    }
  }
  __syncthreads();
  if (t < 128) {
    float x1 = sB1[t], x2 = sB2[t];
    int xi = sBi[t];
    const float y1 = sB1[128 + t], y2 = sB2[128 + t];
    const int yi = sBi[128 + t];
    if (y1 < x1 || (y1 == x1 && yi < xi)) {
      x2 = fminf(x1, y2); x1 = y1; xi = yi;
    } else {
      x2 = fminf(x2, y1);
    }
    const int token = token0 + t;
    outi[(size_t)token * 256] = xi;
    if (x2 - x1 < EPS) {
      const int pos = atomicAdd(&outi[32], 1);
      if (pos < 65536) outi[(size_t)pos * 256 + 64] = token;
    }
  }
}

// ---------------------------------------------------------------------------
// k4: exact fp32 recheck of flagged (small-margin) tokens
// ---------------------------------------------------------------------------
__global__ __launch_bounds__(256) void recheck(const float* __restrict__ x,
                                               const float* __restrict__ cb,
                                               float* __restrict__ outp) {
  __shared__ float sx[256];
  __shared__ float sv[256];
  __shared__ int si[256];
  int* outi = (int*)outp;
  const int t = threadIdx.x;
  const int cnt = min(outi[32], 65536);
  for (int ii = blockIdx.x; ii < cnt; ii += gridDim.x) {
    const int token = outi[(size_t)ii * 256 + 64];
    const int b = token >> 10, hw = token & 1023;
    sx[t] = x[(size_t)b * 262144 + (size_t)t * 1024 + hw];
    __syncthreads();
    float bv = 3.4e38f;
    int bidx = 0;
    #pragma unroll 1
    for (int kk = 0; kk < 4; ++kk) {
      const int k = kk * 256 + t;
      const float* cr = cb + (size_t)k * 256;
      float s = 0.f;
      for (int d = 0; d < 256; d += 4) {
        const float4 cv = *reinterpret_cast<const float4*>(cr + d);
        s = fmaf(sx[d], cv.x, s);
        s = fmaf(sx[d + 1], cv.y, s);
        s = fmaf(sx[d + 2], cv.z, s);
        s = fmaf(sx[d + 3], cv.w, s);
      }
      const float v = outp[(size_t)(2048 + k) * 256 + 128] - s;
      if (v < bv) { bv = v; bidx = k; }
    }
    sv[t] = bv; si[t] = bidx;
    __syncthreads();
    for (int s2 = 128; s2 > 0; s2 >>= 1) {
      if (t < s2) {
        if (sv[t + s2] < sv[t] || (sv[t + s2] == sv[t] && si[t + s2] < si[t])) {
          sv[t] = sv[t + s2]; si[t] = si[t + s2];
        }
      }
      __syncthreads();
    }
    if (t == 0) outi[(size_t)token * 256] = si[0];
    __syncthreads();
  }
}

// ---------------------------------------------------------------------------
// k5: gather codebook rows, write z_hat and z_q
// ---------------------------------------------------------------------------
__global__ __launch_bounds__(256) void gather(const float* __restrict__ cb,
                                              float* __restrict__ outp) {
  __shared__ int sIdx[32];
  const int t = threadIdx.x;
  const int n0 = blockIdx.x << 5;
  int* outi = (int*)outp;
  if (t < 32) sIdx[t] = outi[(size_t)(n0 + t) * 256];
  __syncthreads();
  const int wv = t >> 6, l = t & 63;
  #pragma unroll 1
  for (int rr = 0; rr < 8; ++rr) {
    const int row = wv * 8 + rr;
    const int k = sIdx[row];
    const float4 v = *reinterpret_cast<const float4*>(cb + (size_t)k * 256 + l * 4);
    const size_t n = (size_t)(n0 + row);
    *reinterpret_cast<float4*>(outp + n * 256 + l * 4) = v;
    *reinterpret_cast<float4*>(outp + OUTOFF + n * 256 + l * 4) = v;
  }
}

extern "C" void kernel_launch(void* const* d_in, const int* in_sizes, int n_in,
                              void* d_out, int out_size, void* d_ws, size_t ws_size,
                              hipStream_t stream) {
  const float* x = (const float*)d_in[0];
  const float* cb = (const float*)d_in[1];
  float* out = (float*)d_out;
  prep<<<1024, 64, 0, stream>>>(cb, out);
  xsplit<<<1024, 256, 0, stream>>>(x, out);
  vq_mfma<<<512, 512, 0, stream>>>(out);
  recheck<<<256, 256, 0, stream>>>(x, cb, out);
  gather<<<2048, 256, 0, stream>>>(cb, out);
}

// Round 4
// 371.817 us; speedup vs baseline: 1.6340x; 1.0464x over previous
//
#include <hip/hip_runtime.h>
#include <cstdint>

// B=64, D=256, H=W=32, K=1024 -> N=65536 tokens.
// argmin_k ||x-c_k||^2 == argmin_k (0.5||c_k||^2 - x.c_k)
// GEMM computed SWAPPED: C[code][token] = cb_f16 . x_f16^T (2 passes: x=hi+lo),
// so each lane owns 2 token-columns and the code-argmin is in-register.
//
// Fused path (ws_size >= 65MB): x_hi/x_lo/cb16/cbn/counter/list live in d_ws;
// vq writes final output rows directly; recheck rewrites flagged rows.
// Fallback path: round-3 scratch layout inside d_out + separate gather.
#define OUTOFF 16777216ULL
#define XHI_B 67108864ULL
#define XLO_B 100663296ULL
#define EPS 0.05f

typedef _Float16 f16x8 __attribute__((ext_vector_type(8)));
typedef _Float16 f16x4 __attribute__((ext_vector_type(4)));
typedef float f32x16 __attribute__((ext_vector_type(16)));

__device__ __forceinline__ void gload16(const void* g, void* l) {
  __builtin_amdgcn_global_load_lds(
      (const unsigned int __attribute__((address_space(1)))*)(unsigned long long)(uintptr_t)g,
      (unsigned int __attribute__((address_space(3)))*)(unsigned int)(uintptr_t)l, 16, 0, 0);
}

// ---------------------------------------------------------------------------
// k1: cbn + codebook fp16 conversion + zero flag counter
// ---------------------------------------------------------------------------
__global__ __launch_bounds__(64) void prep(const float* __restrict__ cb,
                                           char* __restrict__ cb16, int rsB,
                                           float* __restrict__ cbn, int cbnStride,
                                           int* __restrict__ counter) {
  const int k = blockIdx.x, l = threadIdx.x;
  if (k == 0 && l == 0) counter[0] = 0;
  const float4 v = *reinterpret_cast<const float4*>(cb + k * 256 + l * 4);
  float s = v.x * v.x + v.y * v.y + v.z * v.z + v.w * v.w;
  #pragma unroll
  for (int m = 32; m >= 1; m >>= 1) s += __shfl_xor(s, m, 64);
  if (l == 0) cbn[(size_t)k * cbnStride] = 0.5f * s;
  f16x4 h;
  h[0] = (_Float16)v.x; h[1] = (_Float16)v.y;
  h[2] = (_Float16)v.z; h[3] = (_Float16)v.w;
  *reinterpret_cast<f16x4*>(cb16 + (size_t)k * rsB + l * 8) = h;
}

// ---------------------------------------------------------------------------
// k2: x [d][tok] fp32 -> token-major fp16 hi/lo via LDS transpose
// ---------------------------------------------------------------------------
__global__ __launch_bounds__(256) void xsplit(const float* __restrict__ x,
                                              char* __restrict__ xh,
                                              char* __restrict__ xl) {
  __shared__ __align__(16) float sX[16384];  // [256 d][64 tok], chunk-XOR swizzled
  const int t = threadIdx.x;
  const int n0 = blockIdx.x << 6;
  const int b = n0 >> 10, hw0 = n0 & 1023;
  const float* xb = x + (size_t)b * 262144 + hw0;
  float4* sX4 = reinterpret_cast<float4*>(sX);
  #pragma unroll
  for (int r = 0; r < 16; ++r) {
    const int d = r * 16 + (t >> 4);
    const int T = t & 15;
    const float4 v = *reinterpret_cast<const float4*>(xb + (size_t)d * 1024 + T * 4);
    sX4[d * 16 + (T ^ ((d >> 3) & 15))] = v;
  }
  __syncthreads();
  #pragma unroll 1
  for (int p = 0; p < 8; ++p) {
    const int tl = p * 8 + (t >> 5);  // token local 0..63
    const int c = t & 31;             // d-chunk: d = c*8..c*8+7
    const int Tr = tl >> 2, ri = tl & 3;
    f16x8 H, L;
    #pragma unroll
    for (int qq = 0; qq < 4; ++qq) {
      const int d0 = c * 8 + qq * 2;
      const float v0 = sX[d0 * 64 + ((Tr ^ (c & 15)) << 2) + ri];
      const float v1 = sX[(d0 + 1) * 64 + ((Tr ^ (c & 15)) << 2) + ri];
      const _Float16 h0 = (_Float16)v0, h1 = (_Float16)v1;
      H[2 * qq] = h0; H[2 * qq + 1] = h1;
      L[2 * qq] = (_Float16)(v0 - (float)h0);
      L[2 * qq + 1] = (_Float16)(v1 - (float)h1);
    }
    const size_t off = (size_t)(n0 + tl) * 512 + c * 16;
    *reinterpret_cast<f16x8*>(xh + off) = H;
    *reinterpret_cast<f16x8*>(xl + off) = L;
  }
}

// ---------------------------------------------------------------------------
// k3: swapped fp16 MFMA distance-GEMM (2-pass) + in-lane top-2 argmin.
// 512 blocks x 512 thr (8 waves: 4m x 2n). Per kt code-tile of 256, BK=64.
// ---------------------------------------------------------------------------
template <int FUSED>
__global__ __launch_bounds__(512, 4) void vq(const char* __restrict__ xh,
                                             const char* __restrict__ xl,
                                             const char* __restrict__ cb16, int rsB,
                                             const float* __restrict__ cbn, int cbnStride,
                                             int* __restrict__ counter,
                                             int* __restrict__ list, int lstride,
                                             float* __restrict__ out,
                                             const float* __restrict__ cb) {
  __shared__ __align__(16) unsigned short sC[16384];   // [256 codes][64 d]
  __shared__ __align__(16) unsigned short sXh[8192];   // [128 tok][64 d]
  __shared__ __align__(16) unsigned short sXl[8192];
  __shared__ float sCbn[1024];
  __shared__ int sIdx[128];

  const int t = threadIdx.x;
  const int w = t >> 6, l = t & 63;
  const int wm = w & 3, wn = w >> 2;           // 4 code-waves x 2 token-waves
  const int l31 = l & 31, lg = l >> 5;
  const int bswz = (blockIdx.x & 7) * 64 + (blockIdx.x >> 3);  // XCD swizzle (512%8==0)
  const int token0 = bswz << 7;
  const int chunk_src = (l & 7) ^ ((l >> 3) & 7);  // pre-swizzled source chunk

  for (int q = t; q < 1024; q += 512) sCbn[q] = cbn[(size_t)q * cbnStride];

  f32x16 acc[2][2];
  float b1[2] = {3.4e38f, 3.4e38f}, b2[2] = {3.4e38f, 3.4e38f};
  int bi[2] = {0, 0};

  #pragma unroll 1
  for (int kt = 0; kt < 4; ++kt) {
    #pragma unroll
    for (int mf = 0; mf < 2; ++mf)
      #pragma unroll
      for (int nf = 0; nf < 2; ++nf)
        #pragma unroll
        for (int r = 0; r < 16; ++r) acc[mf][nf][r] = 0.0f;

    #pragma unroll 1
    for (int dt = 0; dt < 4; ++dt) {
      __syncthreads();
      // stage codes: 32 rows per wave (4 x 8-row groups)
      #pragma unroll
      for (int q = 0; q < 4; ++q) {
        const int row = w * 32 + q * 8;
        const size_t src = (size_t)(kt * 256 + row + (l >> 3)) * rsB + dt * 128 + chunk_src * 16;
        gload16(cb16 + src, &sC[row * 64]);
      }
      // stage x hi/lo: 16 rows per wave each
      #pragma unroll
      for (int q = 0; q < 2; ++q) {
        const int row = w * 16 + q * 8;
        const size_t src = (size_t)(token0 + row + (l >> 3)) * 512 + dt * 128 + chunk_src * 16;
        gload16(xh + src, &sXh[row * 64]);
        gload16(xl + src, &sXl[row * 64]);
      }
      __syncthreads();
      #pragma unroll
      for (int ks = 0; ks < 4; ++ks) {
        const int ch = (2 * ks + lg) ^ (l & 7);  // swizzled chunk (row%8 == l%8)
        f16x8 a[2], bh[2], bl[2];
        #pragma unroll
        for (int mf = 0; mf < 2; ++mf)
          a[mf] = *reinterpret_cast<const f16x8*>(&sC[(wm * 64 + mf * 32 + l31) * 64 + ch * 8]);
        #pragma unroll
        for (int nf = 0; nf < 2; ++nf) {
          const int br = (wn * 64 + nf * 32 + l31) * 64 + ch * 8;
          bh[nf] = *reinterpret_cast<const f16x8*>(&sXh[br]);
          bl[nf] = *reinterpret_cast<const f16x8*>(&sXl[br]);
        }
        #pragma unroll
        for (int mf = 0; mf < 2; ++mf)
          #pragma unroll
          for (int nf = 0; nf < 2; ++nf) {
            acc[mf][nf] = __builtin_amdgcn_mfma_f32_32x32x16_f16(a[mf], bh[nf], acc[mf][nf], 0, 0, 0);
            acc[mf][nf] = __builtin_amdgcn_mfma_f32_32x32x16_f16(a[mf], bl[nf], acc[mf][nf], 0, 0, 0);
          }
      }
    }
    // epilogue: dist = cbn - s ; in-lane top-2 update (codes strictly ascending)
    #pragma unroll
    for (int mf = 0; mf < 2; ++mf) {
      const int cb0 = kt * 256 + wm * 64 + mf * 32 + 4 * lg;
      #pragma unroll
      for (int r = 0; r < 16; ++r) {
        const int code = cb0 + (r & 3) + 8 * (r >> 2);
        const float cn = sCbn[code];
        #pragma unroll
        for (int nf = 0; nf < 2; ++nf) {
          const float v = cn - acc[mf][nf][r];
          if (v < b1[nf]) { b2[nf] = b1[nf]; b1[nf] = v; bi[nf] = code; }
          else if (v < b2[nf]) b2[nf] = v;
        }
      }
    }
  }

  // merge the two half-lane views (lanes l and l^32 share token columns)
  #pragma unroll
  for (int nf = 0; nf < 2; ++nf) {
    const float o1 = __shfl_xor(b1[nf], 32, 64);
    const float o2 = __shfl_xor(b2[nf], 32, 64);
    const int oi = __shfl_xor(bi[nf], 32, 64);
    if (o1 < b1[nf] || (o1 == b1[nf] && oi < bi[nf])) {
      b2[nf] = fminf(b1[nf], o2); b1[nf] = o1; bi[nf] = oi;
    } else {
      b2[nf] = fminf(b2[nf], o1);
    }
  }

  // cross-wave (4 code-wave groups) combine via LDS (alias dead sC)
  __syncthreads();
  float* sR1 = reinterpret_cast<float*>(sC);   // [128][4]
  float* sR2 = sR1 + 512;
  int* sRi = reinterpret_cast<int*>(sR2 + 512);
  if (l < 32) {
    #pragma unroll
    for (int nf = 0; nf < 2; ++nf) {
      const int tok = wn * 64 + nf * 32 + l;
      sR1[tok * 4 + wm] = b1[nf];
      sR2[tok * 4 + wm] = b2[nf];
      sRi[tok * 4 + wm] = bi[nf];
    }
  }
  __syncthreads();
  if (t < 128) {
    float v1 = sR1[t * 4], v2 = sR2[t * 4];
    int vi = sRi[t * 4];
    #pragma unroll
    for (int q = 1; q < 4; ++q) {
      const float o1 = sR1[t * 4 + q], o2 = sR2[t * 4 + q];
      const int oi = sRi[t * 4 + q];
      if (o1 < v1 || (o1 == v1 && oi < vi)) { v2 = fminf(v1, o2); v1 = o1; vi = oi; }
      else v2 = fminf(v2, o1);
    }
    sIdx[t] = vi;
    if (v2 - v1 < EPS) {
      const int pos = atomicAdd(counter, 1);
      if (pos < 65536) list[(size_t)pos * lstride] = token0 + t;
    }
    if (!FUSED) reinterpret_cast<int*>(out)[(size_t)(token0 + t) * 256] = vi;
  }
  __syncthreads();
  if (FUSED) {
    // write both outputs: per wave 16 rows, 1KB per wave-instruction
    #pragma unroll 1
    for (int rr = 0; rr < 16; ++rr) {
      const int tok = w * 16 + rr;
      const int k = sIdx[tok];
      const float4 v = *reinterpret_cast<const float4*>(cb + (size_t)k * 256 + l * 4);
      const size_t n = (size_t)(token0 + tok);
      *reinterpret_cast<float4*>(out + n * 256 + l * 4) = v;
      *reinterpret_cast<float4*>(out + OUTOFF + n * 256 + l * 4) = v;
    }
  }
}

// ---------------------------------------------------------------------------
// k4: exact fp32 recheck of flagged (small-margin) tokens
// ---------------------------------------------------------------------------
template <int FUSED>
__global__ __launch_bounds__(256) void recheck(const float* __restrict__ x,
                                               const float* __restrict__ cb,
                                               const float* __restrict__ cbn, int cbnStride,
                                               const int* __restrict__ counter,
                                               const int* __restrict__ list, int lstride,
                                               float* __restrict__ out) {
  __shared__ float sx[256];
  __shared__ float sv[256];
  __shared__ int si[256];
  const int t = threadIdx.x;
  const int cnt = min(counter[0], 65536);
  for (int ii = blockIdx.x; ii < cnt; ii += gridDim.x) {
    const int token = list[(size_t)ii * lstride];
    const int b = token >> 10, hw = token & 1023;
    sx[t] = x[(size_t)b * 262144 + (size_t)t * 1024 + hw];
    __syncthreads();
    float bv = 3.4e38f;
    int bidx = 0;
    #pragma unroll 1
    for (int kk = 0; kk < 4; ++kk) {
      const int k = kk * 256 + t;
      const float* cr = cb + (size_t)k * 256;
      float s = 0.f;
      for (int d = 0; d < 256; d += 4) {
        const float4 cv = *reinterpret_cast<const float4*>(cr + d);
        s = fmaf(sx[d], cv.x, s);
        s = fmaf(sx[d + 1], cv.y, s);
        s = fmaf(sx[d + 2], cv.z, s);
        s = fmaf(sx[d + 3], cv.w, s);
      }
      const float v = cbn[(size_t)k * cbnStride] - s;
      if (v < bv) { bv = v; bidx = k; }
    }
    sv[t] = bv; si[t] = bidx;
    __syncthreads();
    for (int s2 = 128; s2 > 0; s2 >>= 1) {
      if (t < s2) {
        if (sv[t + s2] < sv[t] || (sv[t + s2] == sv[t] && si[t + s2] < si[t])) {
          sv[t] = sv[t + s2]; si[t] = si[t + s2];
        }
      }
      __syncthreads();
    }
    const int best = si[0];
    if (FUSED) {
      const float* crow = cb + (size_t)best * 256;
      out[(size_t)token * 256 + t] = crow[t];
      out[OUTOFF + (size_t)token * 256 + t] = crow[t];
    } else if (t == 0) {
      reinterpret_cast<int*>(out)[(size_t)token * 256] = best;
    }
    __syncthreads();
  }
}

// ---------------------------------------------------------------------------
// k5 (fallback only): gather codebook rows, write z_hat and z_q
// ---------------------------------------------------------------------------
__global__ __launch_bounds__(256) void gather(const float* __restrict__ cb,
                                              float* __restrict__ outp) {
  __shared__ int sI[32];
  const int t = threadIdx.x;
  const int n0 = blockIdx.x << 5;
  int* outi = (int*)outp;
  if (t < 32) sI[t] = outi[(size_t)(n0 + t) * 256];
  __syncthreads();
  const int wv = t >> 6, l = t & 63;
  #pragma unroll 1
  for (int rr = 0; rr < 8; ++rr) {
    const int row = wv * 8 + rr;
    const int k = sI[row];
    const float4 v = *reinterpret_cast<const float4*>(cb + (size_t)k * 256 + l * 4);
    const size_t n = (size_t)(n0 + row);
    *reinterpret_cast<float4*>(outp + n * 256 + l * 4) = v;
    *reinterpret_cast<float4*>(outp + OUTOFF + n * 256 + l * 4) = v;
  }
}

extern "C" void kernel_launch(void* const* d_in, const int* in_sizes, int n_in,
                              void* d_out, int out_size, void* d_ws, size_t ws_size,
                              hipStream_t stream) {
  const float* x = (const float*)d_in[0];
  const float* cb = (const float*)d_in[1];
  float* out = (float*)d_out;
  char* outb = (char*)d_out;
  char* wsb = (char*)d_ws;

  const bool fused = (ws_size >= 0x4100000ULL) && (d_ws != nullptr);
  char *xh, *xl, *cb16;
  float* cbn;
  int *counter, *list;
  int rsB, cbnStride, lstride;
  if (fused) {
    xh = wsb;                      // 32MB
    xl = wsb + 0x2000000;          // 32MB
    cb16 = wsb + 0x4000000;        // 512KB
    rsB = 512;
    cbn = (float*)(wsb + 0x4080000);  // 4KB
    cbnStride = 1;
    counter = (int*)(wsb + 0x4081000);
    list = counter + 16;           // 256KB
    lstride = 1;
  } else {
    xh = outb + XHI_B;
    xl = outb + XLO_B;
    cb16 = outb + 512;             // rows k*1024+512 (round-3 layout)
    rsB = 1024;
    cbn = (float*)(outb + 2048 * 1024 + 512);
    cbnStride = 256;
    counter = (int*)d_out + 32;
    list = (int*)d_out + 64;
    lstride = 256;
  }

  prep<<<1024, 64, 0, stream>>>(cb, cb16, rsB, cbn, cbnStride, counter);
  xsplit<<<1024, 256, 0, stream>>>(x, xh, xl);
  if (fused) {
    vq<1><<<512, 512, 0, stream>>>(xh, xl, cb16, rsB, cbn, cbnStride, counter, list, lstride, out, cb);
    recheck<1><<<256, 256, 0, stream>>>(x, cb, cbn, cbnStride, counter, list, lstride, out);
  } else {
    vq<0><<<512, 512, 0, stream>>>(xh, xl, cb16, rsB, cbn, cbnStride, counter, list, lstride, out, cb);
    recheck<0><<<256, 256, 0, stream>>>(x, cb, cbn, cbnStride, counter, list, lstride, out);
    gather<<<2048, 256, 0, stream>>>(cb, out);
  }
}